// Round 7
// baseline (6478.925 us; speedup 1.0000x reference)
//
#include <hip/hip_runtime.h>
#include <cstdint>
#include <cstddef>

// Problem constants (fixed by the reference).
#define B_   2048
#define T_   100
#define U_   512
#define NG_  2048   // 4*U
#define C_   10

typedef __attribute__((ext_vector_type(8))) short   short8;
typedef __attribute__((ext_vector_type(4))) float   floatx4;
typedef unsigned short ushort_t;

__device__ inline ushort_t f2bf(float f){
  unsigned u = __float_as_uint(f);
  unsigned r = (u + 0x7FFFu + ((u >> 16) & 1u)) >> 16;   // RNE
  return (ushort_t)r;
}
__device__ inline float bf2f(ushort_t b){ return __uint_as_float(((unsigned)b) << 16); }

__device__ inline float sigm(float x){ return 1.0f / (1.0f + __expf(-x)); }
__device__ inline float tanh_fast(float x){
  float a = fabsf(x);
  float e = __expf(-2.0f * a);          // no overflow: e in (0,1]
  float r = (1.0f - e) / (1.0f + e);
  return copysignf(r, x);
}

// Column permutation: permuted col p -> original gate-major col.
// 128-col group owns u in [G*32, G*32+32); within group: two 64-col halves,
// each half = 4 gates x 16 u's, gate-major in 16-col groups.
__device__ inline int orig_col(int p){
  int Tt  = p >> 7;
  int loc = p & 127;
  int half = loc >> 6;
  int loc2 = loc & 63;
  int gate = loc2 >> 4;
  int uu   = (half << 4) | (loc2 & 15);
  return gate * U_ + Tt * 32 + uu;
}

#define AS1(p) ((const __attribute__((address_space(1))) void*)(p))
#define AS3(p) ((__attribute__((address_space(3))) void*)(p))

// ---------------------------------------------------------------------------
// One-time (per launch) weight repack: fp32 -> bf16, B^T (n-major) layout with
// gate-interleaved column permutation. Also permuted biases (fp32) and W0 row.
// ---------------------------------------------------------------------------
__global__ void convert_weights(
    const float* __restrict__ W0, const float* __restrict__ U0, const float* __restrict__ b0,
    const float* __restrict__ W1, const float* __restrict__ U1, const float* __restrict__ b1,
    const float* __restrict__ W2, const float* __restrict__ U2, const float* __restrict__ b2,
    ushort_t* __restrict__ Bt0, ushort_t* __restrict__ Bt1, ushort_t* __restrict__ Bt2,
    float* __restrict__ W0p, float* __restrict__ biasp)
{
  const int N0 = NG_ * 512;     // Bt0 elements
  const int N1 = NG_ * 1024;    // Bt1/Bt2 elements
  const int total = N0 + 2 * N1 + NG_ + 3 * NG_;
  int idx = blockIdx.x * 256 + threadIdx.x;
  if (idx >= total) return;

  if (idx < N0){
    int p = idx >> 9, k = idx & 511;
    Bt0[idx] = f2bf(U0[(size_t)k * NG_ + orig_col(p)]);
  } else if (idx < N0 + N1){
    int j = idx - N0; int p = j >> 10, k = j & 1023;
    int oc = orig_col(p);
    float v = (k < 512) ? W1[(size_t)k * NG_ + oc] : U1[(size_t)(k - 512) * NG_ + oc];
    Bt1[j] = f2bf(v);
  } else if (idx < N0 + 2 * N1){
    int j = idx - N0 - N1; int p = j >> 10, k = j & 1023;
    int oc = orig_col(p);
    float v = (k < 512) ? W2[(size_t)k * NG_ + oc] : U2[(size_t)(k - 512) * NG_ + oc];
    Bt2[j] = f2bf(v);
  } else if (idx < N0 + 2 * N1 + NG_){
    int p = idx - N0 - 2 * N1;
    W0p[p] = W0[orig_col(p)];
  } else {
    int j = idx - N0 - 2 * N1 - NG_;
    int l = j >> 11, p = j & 2047;
    const float* bs = (l == 0) ? b0 : (l == 1) ? b1 : b2;
    biasp[j] = bs[orig_col(p)];
  }
}

// ---------------------------------------------------------------------------
// Fused GEMM (bf16 MFMA) + LSTM cell for one (layer, timestep).
// 64x128 tile (BM=64 -> 512 tiles/task -> 6 blocks/CU: round-4/5/6 lesson is
// that independent block-streams per CU, not per-stream pipelining, hide the
// vmcnt(0) barrier drain). BK=64, 2-barrier K-loop, mod-8 slot rotation
// (slot j of row r holds source chunk (j+r)&7 -> readback (q-r)&7; 2-way
// conflicts only = free, verified 0 in r5/r6 counters).
// 256 threads = 2x2 waves, each wave 2x4 frags of 16x16x32, 2 k-steps/iter.
// ---------------------------------------------------------------------------
template<int LAYER>
__device__ __forceinline__ void do_task(
    const ushort_t* __restrict__ A0,   // phase-0 A (h_below / h_prev for L0)
    const ushort_t* __restrict__ A1,   // phase-1 A (h_prev), LAYER>0
    const ushort_t* __restrict__ Bt,   // (2048 x K) bf16, n-major permuted
    const float* __restrict__ biasp,   // permuted bias for this layer (2048)
    const float* __restrict__ W0p,     // permuted W0 row (L0 only)
    const float* __restrict__ x,       // (B,T) fp32 (L0 only)
    const int* __restrict__ mask,      // (B,T) int32
    float* __restrict__ cbuf,          // (B,U) fp32, in/out
    const ushort_t* __restrict__ hprev,// this layer's previous h (mask carry)
    ushort_t* __restrict__ hout,       // (B,U) bf16 out
    int t, int mt, int nt,
    ushort_t* tA, ushort_t* tB)        // 64x64 and 128x64 elements
{
  constexpr int NPHASE = (LAYER == 0) ? 1 : 2;
  constexpr bool IS_L0 = (LAYER == 0);
  constexpr int K = NPHASE * 512;

  const int tid  = threadIdx.x;
  const int wv   = tid >> 6;
  const int lane = tid & 63;
  const int qd   = lane >> 4;     // quad 0..3
  const int l16  = lane & 15;
  const int wave_m = wv >> 1;     // 0..1
  const int wave_n = wv & 1;      // 0..1
  const int m0 = mt * 64, n0 = nt * 128;

  // Staging identities. A: 512 16B-chunks (64 rows x 8), 2/thread.
  // B: 1024 chunks (128 rows x 8), 4/thread. Source col sc = ((i&7)+r)&7.
  int arow[2], acol[2];
  #pragma unroll
  for (int g = 0; g < 2; ++g){
    int i = g * 256 + tid;
    arow[g] = i >> 3;
    acol[g] = ((i & 7) + (i >> 3)) & 7;
  }
  int brow[4], bcol[4];
  #pragma unroll
  for (int g = 0; g < 4; ++g){
    int i = g * 256 + tid;
    brow[g] = i >> 3;
    bcol[g] = ((i & 7) + (i >> 3)) & 7;
  }

  // Readback offsets: frag row R, global chunk q = ks*4+qd at slot (q-R)&7.
  int aoff[2][2], boff[2][4];
  #pragma unroll
  for (int ks = 0; ks < 2; ++ks){
    int q = ks * 4 + qd;
    #pragma unroll
    for (int w = 0; w < 2; ++w){
      int Ra = wave_m * 32 + w * 16 + l16;
      aoff[ks][w] = Ra * 64 + ((q - Ra) & 7) * 8;
    }
    #pragma unroll
    for (int w = 0; w < 4; ++w){
      int Rb = wave_n * 64 + w * 16 + l16;
      boff[ks][w] = Rb * 64 + ((q - Rb) & 7) * 8;
    }
  }

  floatx4 acc[2][4];
  #pragma unroll
  for (int i = 0; i < 2; ++i)
    #pragma unroll
    for (int j = 0; j < 4; ++j) acc[i][j] = (floatx4){0.f, 0.f, 0.f, 0.f};

  #pragma unroll
  for (int ph = 0; ph < NPHASE; ++ph){
    const ushort_t* A = (NPHASE == 2 && ph == 1) ? A1 : A0;
    for (int k0 = 0; k0 < 512; k0 += 64){
      #pragma unroll
      for (int g = 0; g < 2; ++g){
        int ibase = g * 256 + wv * 64;
        const ushort_t* ga = A + (size_t)(m0 + arow[g]) * U_ + k0 + acol[g] * 8;
        __builtin_amdgcn_global_load_lds(AS1(ga), AS3(&tA[ibase * 8]), 16, 0, 0);
      }
      #pragma unroll
      for (int g = 0; g < 4; ++g){
        int ibase = g * 256 + wv * 64;
        const ushort_t* gb = Bt + (size_t)(n0 + brow[g]) * K + ph * 512 + k0 + bcol[g] * 8;
        __builtin_amdgcn_global_load_lds(AS1(gb), AS3(&tB[ibase * 8]), 16, 0, 0);
      }
      __syncthreads();

      #pragma unroll
      for (int ks = 0; ks < 2; ++ks){
        short8 af[2], bfr[4];
        #pragma unroll
        for (int wm = 0; wm < 2; ++wm) af[wm] = *(const short8*)&tA[aoff[ks][wm]];
        #pragma unroll
        for (int wn = 0; wn < 4; ++wn) bfr[wn] = *(const short8*)&tB[boff[ks][wn]];
        #pragma unroll
        for (int wm = 0; wm < 2; ++wm)
          #pragma unroll
          for (int wn = 0; wn < 4; ++wn)
            acc[wm][wn] = __builtin_amdgcn_mfma_f32_16x16x32_bf16(af[wm], bfr[wn], acc[wm][wn], 0, 0, 0);
      }
      __syncthreads();
    }
  }

  // ---- epilogue: LSTM cell, fully in-register per lane (8 batch rows) ----
  const int u  = nt * 32 + wave_n * 16 + l16;
  const int pb = nt * 128 + wave_n * 64 + l16;
  const float bi = biasp[pb], bf_ = biasp[pb + 16], bg = biasp[pb + 32], bo = biasp[pb + 48];
  float wi = 0.f, wf = 0.f, wg = 0.f, wo = 0.f;
  if (IS_L0){ wi = W0p[pb]; wf = W0p[pb + 16]; wg = W0p[pb + 32]; wo = W0p[pb + 48]; }

  #pragma unroll
  for (int wm = 0; wm < 2; ++wm){
    #pragma unroll
    for (int reg = 0; reg < 4; ++reg){
      int b = m0 + wave_m * 32 + wm * 16 + qd * 4 + reg;
      float zi = acc[wm][0][reg] + bi;
      float zf = acc[wm][1][reg] + bf_;
      float zg = acc[wm][2][reg] + bg;
      float zo = acc[wm][3][reg] + bo;
      if (IS_L0){
        float xv = x[(size_t)b * T_ + t];
        zi += xv * wi; zf += xv * wf; zg += xv * wg; zo += xv * wo;
      }
      int mk = mask[(size_t)b * T_ + t];
      size_t su = (size_t)b * U_ + u;
      float c_old = cbuf[su];
      float i_ = sigm(zi), f_ = sigm(zf), g_ = tanh_fast(zg), o_ = sigm(zo);
      float c_new = f_ * c_old + i_ * g_;
      float h_new = o_ * tanh_fast(c_new);
      ushort_t hb = mk ? f2bf(h_new) : hprev[su];
      cbuf[su] = mk ? c_new : c_old;
      hout[su] = hb;
    }
  }
}

// ---------------------------------------------------------------------------
// One wavefront phase: L0(t=s), L1(t=s-1), L2(t=s-2) independent.
// Grid = 1536 blocks (3 tasks x 512 tiles of 64x128) = 6 blocks/CU
// (24 waves/CU): six independent streams cover each other's barrier drains.
// XCD = lin%8 = nt%8 -> each XCD's B working set is ~1.25 MB, L2-resident
// across all 102 phases.
// ---------------------------------------------------------------------------
__global__ __launch_bounds__(256, 6) void lstm_phase(
    const ushort_t* __restrict__ Bt0, const ushort_t* __restrict__ Bt1,
    const ushort_t* __restrict__ Bt2, const float* __restrict__ biasp,
    const float* __restrict__ W0p, const float* __restrict__ x,
    const int* __restrict__ mask,
    ushort_t* h00, ushort_t* h01, ushort_t* h10, ushort_t* h11,
    ushort_t* h20, ushort_t* h21,
    float* c0, float* c1, float* c2,
    int s)
{
  __shared__ __align__(16) ushort_t tA[64 * 64];    //  8 KB
  __shared__ __align__(16) ushort_t tB[128 * 64];   // 16 KB

  const int lin  = blockIdx.x;
  const int task = lin >> 9;        // 0..2
  const int tile = lin & 511;       // 0..511
  const int mt = tile >> 4, nt = tile & 15;

  ushort_t* h0[2] = {h00, h01};
  ushort_t* h1[2] = {h10, h11};
  ushort_t* h2[2] = {h20, h21};

  if (task == 0){
    if (s >= 100) return;
    int t = s, p = t & 1;
    do_task<0>(h0[p], nullptr, Bt0, biasp, W0p, x, mask,
               c0, h0[p], h0[p ^ 1], t, mt, nt, tA, tB);
  } else if (task == 1){
    if (s < 1 || s > 100) return;
    int t = s - 1, p = t & 1;
    do_task<1>(h0[p ^ 1], h1[p], Bt1, biasp + NG_, nullptr, x, mask,
               c1, h1[p], h1[p ^ 1], t, mt, nt, tA, tB);
  } else {
    if (s < 2) return;
    int t = s - 2, p = t & 1;
    do_task<2>(h1[p ^ 1], h2[p], Bt2, biasp + 2 * NG_, nullptr, x, mask,
               c2, h2[p], h2[p ^ 1], t, mt, nt, tA, tB);
  }
}

// ---------------------------------------------------------------------------
// Head: logits = h2 @ Wd + bd, softmax. One wave per batch row.
// ---------------------------------------------------------------------------
__global__ __launch_bounds__(256) void head_softmax(
    const ushort_t* __restrict__ h2, const float* __restrict__ Wd,
    const float* __restrict__ bd, float* __restrict__ out)
{
  int wv = threadIdx.x >> 6, lane = threadIdx.x & 63;
  int row = blockIdx.x * 4 + wv;
  const ushort_t* hr = h2 + (size_t)row * U_;

  float acc[C_];
  #pragma unroll
  for (int c = 0; c < C_; ++c) acc[c] = 0.f;

  short8 hv = *(const short8*)&hr[lane * 8];
  #pragma unroll
  for (int j = 0; j < 8; ++j){
    float hf = bf2f((ushort_t)hv[j]);
    int k = lane * 8 + j;
    #pragma unroll
    for (int c = 0; c < C_; ++c) acc[c] += hf * Wd[k * C_ + c];
  }
  #pragma unroll
  for (int c = 0; c < C_; ++c){
    float v = acc[c];
    #pragma unroll
    for (int off = 32; off > 0; off >>= 1) v += __shfl_xor(v, off);
    acc[c] = v + bd[c];
  }
  float mx = acc[0];
  #pragma unroll
  for (int c = 1; c < C_; ++c) mx = fmaxf(mx, acc[c]);
  float e[C_]; float s = 0.f;
  #pragma unroll
  for (int c = 0; c < C_; ++c){ e[c] = __expf(acc[c] - mx); s += e[c]; }
  float inv = 1.0f / s;
  if (lane == 0){
    #pragma unroll
    for (int c = 0; c < C_; ++c) out[(size_t)row * C_ + c] = e[c] * inv;
  }
}

// ---------------------------------------------------------------------------
extern "C" void kernel_launch(void* const* d_in, const int* in_sizes, int n_in,
                              void* d_out, int out_size, void* d_ws, size_t ws_size,
                              hipStream_t stream)
{
  const float* x  = (const float*)d_in[0];
  const int*  mask= (const int*)  d_in[1];
  const float* W0 = (const float*)d_in[2];
  const float* U0 = (const float*)d_in[3];
  const float* b0 = (const float*)d_in[4];
  const float* W1 = (const float*)d_in[5];
  const float* U1 = (const float*)d_in[6];
  const float* b1 = (const float*)d_in[7];
  const float* W2 = (const float*)d_in[8];
  const float* U2 = (const float*)d_in[9];
  const float* b2 = (const float*)d_in[10];
  const float* Wd = (const float*)d_in[11];
  const float* bd = (const float*)d_in[12];
  float* out = (float*)d_out;

  char* ws = (char*)d_ws;
  size_t off = 0;
  auto alloc = [&](size_t sz) -> char* {
    char* p = ws + off; off = (off + sz + 255) & ~(size_t)255; return p;
  };
  ushort_t* Bt0  = (ushort_t*)alloc((size_t)NG_ * 512 * 2);
  ushort_t* Bt1  = (ushort_t*)alloc((size_t)NG_ * 1024 * 2);
  ushort_t* Bt2  = (ushort_t*)alloc((size_t)NG_ * 1024 * 2);
  float*    W0p  = (float*)alloc((size_t)NG_ * 4);
  float*    biasp= (float*)alloc((size_t)3 * NG_ * 4);

  // State: h[3][2] (bf16) + c[3] (fp32), one contiguous memset region.
  const size_t hsz = (size_t)B_ * U_ * 2;
  const size_t csz = (size_t)B_ * U_ * 4;
  char* state = alloc(6 * hsz + 3 * csz);
  ushort_t* hb[3][2]; float* cb[3];
  {
    char* pp = state;
    for (int l = 0; l < 3; ++l)
      for (int par = 0; par < 2; ++par){ hb[l][par] = (ushort_t*)pp; pp += hsz; }
    for (int l = 0; l < 3; ++l){ cb[l] = (float*)pp; pp += csz; }
  }

  hipMemsetAsync(state, 0, 6 * hsz + 3 * csz, stream);

  const int total = NG_ * 512 + 2 * NG_ * 1024 + NG_ + 3 * NG_;
  convert_weights<<<(total + 255) / 256, 256, 0, stream>>>(
      W0, U0, b0, W1, U1, b1, W2, U2, b2, Bt0, Bt1, Bt2, W0p, biasp);

  for (int s = 0; s < 102; ++s){
    lstm_phase<<<1536, 256, 0, stream>>>(
        Bt0, Bt1, Bt2, biasp, W0p, x, mask,
        hb[0][0], hb[0][1], hb[1][0], hb[1][1], hb[2][0], hb[2][1],
        cb[0], cb[1], cb[2], s);
  }

  // T=100: layer-2 final h (t=99) lands in parity-0 buffer.
  head_softmax<<<B_ / 4, 256, 0, stream>>>(hb[2][0], Wd, bd, out);
}

// Round 8
// 5219.172 us; speedup vs baseline: 1.2414x; 1.2414x over previous
//
#include <hip/hip_runtime.h>
#include <cstdint>
#include <cstddef>

// Problem constants (fixed by the reference).
#define B_   2048
#define T_   100
#define U_   512
#define NG_  2048   // 4*U
#define C_   10

typedef __attribute__((ext_vector_type(8))) short   short8;
typedef __attribute__((ext_vector_type(4))) float   floatx4;
typedef unsigned short ushort_t;

__device__ inline ushort_t f2bf(float f){
  unsigned u = __float_as_uint(f);
  unsigned r = (u + 0x7FFFu + ((u >> 16) & 1u)) >> 16;   // RNE
  return (ushort_t)r;
}
__device__ inline float bf2f(ushort_t b){ return __uint_as_float(((unsigned)b) << 16); }

// fp16 storage for c-state: |c| <= ~100, fp16 rel-err 2^-11 — negligible vs
// bf16 GEMM noise; halves c-state HBM/L3 traffic (round-7 lesson: this
// decomposition is at its traffic floor; cut the bytes, not the structure).
__device__ inline ushort_t f2h(float f){
  _Float16 h = (_Float16)f;
  return __builtin_bit_cast(ushort_t, h);
}
__device__ inline float h2f(ushort_t u){
  _Float16 h = __builtin_bit_cast(_Float16, u);
  return (float)h;
}

__device__ inline float sigm(float x){ return 1.0f / (1.0f + __expf(-x)); }
__device__ inline float tanh_fast(float x){
  float a = fabsf(x);
  float e = __expf(-2.0f * a);          // no overflow: e in (0,1]
  float r = (1.0f - e) / (1.0f + e);
  return copysignf(r, x);
}

// Column permutation: permuted col p -> original gate-major col.
// Tile T (128 cols) owns u in [T*32, T*32+32); within tile: two 64-col halves,
// each half = 4 gates x 16 u's, gate-major in 16-col groups.
__device__ inline int orig_col(int p){
  int Tt  = p >> 7;
  int loc = p & 127;
  int half = loc >> 6;
  int loc2 = loc & 63;
  int gate = loc2 >> 4;
  int uu   = (half << 4) | (loc2 & 15);
  return gate * U_ + Tt * 32 + uu;
}

#define AS1(p) ((const __attribute__((address_space(1))) void*)(p))
#define AS3(p) ((__attribute__((address_space(3))) void*)(p))

// ---------------------------------------------------------------------------
// One-time (per launch) weight repack: fp32 -> bf16, B^T (n-major) layout with
// gate-interleaved column permutation. Also permuted biases (fp32) and W0 row.
// ---------------------------------------------------------------------------
__global__ void convert_weights(
    const float* __restrict__ W0, const float* __restrict__ U0, const float* __restrict__ b0,
    const float* __restrict__ W1, const float* __restrict__ U1, const float* __restrict__ b1,
    const float* __restrict__ W2, const float* __restrict__ U2, const float* __restrict__ b2,
    ushort_t* __restrict__ Bt0, ushort_t* __restrict__ Bt1, ushort_t* __restrict__ Bt2,
    float* __restrict__ W0p, float* __restrict__ biasp)
{
  const int N0 = NG_ * 512;     // Bt0 elements
  const int N1 = NG_ * 1024;    // Bt1/Bt2 elements
  const int total = N0 + 2 * N1 + NG_ + 3 * NG_;
  int idx = blockIdx.x * 256 + threadIdx.x;
  if (idx >= total) return;

  if (idx < N0){
    int p = idx >> 9, k = idx & 511;
    Bt0[idx] = f2bf(U0[(size_t)k * NG_ + orig_col(p)]);
  } else if (idx < N0 + N1){
    int j = idx - N0; int p = j >> 10, k = j & 1023;
    int oc = orig_col(p);
    float v = (k < 512) ? W1[(size_t)k * NG_ + oc] : U1[(size_t)(k - 512) * NG_ + oc];
    Bt1[j] = f2bf(v);
  } else if (idx < N0 + 2 * N1){
    int j = idx - N0 - N1; int p = j >> 10, k = j & 1023;
    int oc = orig_col(p);
    float v = (k < 512) ? W2[(size_t)k * NG_ + oc] : U2[(size_t)(k - 512) * NG_ + oc];
    Bt2[j] = f2bf(v);
  } else if (idx < N0 + 2 * N1 + NG_){
    int p = idx - N0 - 2 * N1;
    W0p[p] = W0[orig_col(p)];
  } else {
    int j = idx - N0 - 2 * N1 - NG_;
    int l = j >> 11, p = j & 2047;
    const float* bs = (l == 0) ? b0 : (l == 1) ? b1 : b2;
    biasp[j] = bs[orig_col(p)];
  }
}

// ---------------------------------------------------------------------------
// Fused GEMM (bf16 MFMA) + LSTM cell for one (layer, timestep),
// 128x128 tile at (mt, nt). BK=64 2-barrier K-loop (round-4 winner; dbuf,
// BK=32, wide and small tiles all regressed). Slot rotation: LDS slot (r,j)
// holds global 16B-chunk (j+r)&7, readback (q-r)&7 -> conflicts measured 0.
// Epilogue operands (c_old/mask/hprev/x) prefetched at loop start so the
// post-MFMA tail is store-only.
// 256 threads = 2x2 waves, each wave 4x4 frags of 16x16x32, 2 k-steps/iter.
// ---------------------------------------------------------------------------
template<int LAYER>
__device__ __forceinline__ void do_task(
    const ushort_t* __restrict__ A0,   // phase-0 A (h_below / h_prev for L0)
    const ushort_t* __restrict__ A1,   // phase-1 A (h_prev), LAYER>0
    const ushort_t* __restrict__ Bt,   // (2048 x K) bf16, n-major permuted
    const float* __restrict__ biasp,   // permuted bias for this layer (2048)
    const float* __restrict__ W0p,     // permuted W0 row (L0 only)
    const float* __restrict__ x,       // (B,T) fp32 (L0 only)
    const int* __restrict__ mask,      // (B,T) int32
    ushort_t* __restrict__ cbuf,       // (B,U) fp16, in/out
    const ushort_t* __restrict__ hprev,// this layer's previous h (mask carry)
    ushort_t* __restrict__ hout,       // (B,U) bf16 out
    int t, int mt, int nt,
    ushort_t* tA, ushort_t* tB)
{
  constexpr int NPHASE = (LAYER == 0) ? 1 : 2;
  constexpr bool IS_L0 = (LAYER == 0);
  constexpr int K = NPHASE * 512;

  const int tid  = threadIdx.x;
  const int wv   = tid >> 6;
  const int lane = tid & 63;
  const int qd   = lane >> 4;     // quad 0..3
  const int l16  = lane & 15;
  const int wave_m = wv >> 1;     // 0..1
  const int wave_n = wv & 1;      // 0..1
  const int m0 = mt * 128, n0 = nt * 128;

  // Staging identity: 1024 16B-chunks per 128x64 tile, 4/thread.
  // Source 16B-col sc = ((i&7) + r) & 7  (row rotation).
  int srow[4], scol[4];
  #pragma unroll
  for (int g = 0; g < 4; ++g){
    int i = g * 256 + tid;
    srow[g] = i >> 3;
    scol[g] = ((i & 7) + (i >> 3)) & 7;
  }

  // Readback: frag row R wants global chunk q = ks*4+qd at slot (q-R)&7.
  int aoff[2][4], boff[2][4];
  #pragma unroll
  for (int ks = 0; ks < 2; ++ks){
    int q = ks * 4 + qd;
    #pragma unroll
    for (int w = 0; w < 4; ++w){
      int Ra = wave_m * 64 + w * 16 + l16;
      int Rb = wave_n * 64 + w * 16 + l16;
      aoff[ks][w] = Ra * 64 + ((q - Ra) & 7) * 8;
      boff[ks][w] = Rb * 64 + ((q - Rb) & 7) * 8;
    }
  }

  // ---- prefetch epilogue operands (overlap with the GEMM) ----
  const int u = nt * 32 + wave_n * 16 + l16;
  int   mk[4][4];
  ushort_t c_raw[4][4];
  ushort_t hp[4][4];
  float xv[4][4];
  #pragma unroll
  for (int wm = 0; wm < 4; ++wm){
    #pragma unroll
    for (int reg = 0; reg < 4; ++reg){
      int b = m0 + wave_m * 64 + wm * 16 + qd * 4 + reg;
      size_t su = (size_t)b * U_ + u;
      mk[wm][reg]    = mask[(size_t)b * T_ + t];
      c_raw[wm][reg] = cbuf[su];
      hp[wm][reg]    = hprev[su];
      if (IS_L0) xv[wm][reg] = x[(size_t)b * T_ + t];
    }
  }

  floatx4 acc[4][4];
  #pragma unroll
  for (int i = 0; i < 4; ++i)
    #pragma unroll
    for (int j = 0; j < 4; ++j) acc[i][j] = (floatx4){0.f, 0.f, 0.f, 0.f};

  #pragma unroll
  for (int ph = 0; ph < NPHASE; ++ph){
    const ushort_t* A = (NPHASE == 2 && ph == 1) ? A1 : A0;
    for (int k0 = 0; k0 < 512; k0 += 64){
      #pragma unroll
      for (int g = 0; g < 4; ++g){
        int ibase = g * 256 + wv * 64;
        const ushort_t* ga = A + (size_t)(m0 + srow[g]) * U_ + k0 + scol[g] * 8;
        __builtin_amdgcn_global_load_lds(AS1(ga), AS3(&tA[ibase * 8]), 16, 0, 0);
        const ushort_t* gb = Bt + (size_t)(n0 + srow[g]) * K + ph * 512 + k0 + scol[g] * 8;
        __builtin_amdgcn_global_load_lds(AS1(gb), AS3(&tB[ibase * 8]), 16, 0, 0);
      }
      __syncthreads();

      #pragma unroll
      for (int ks = 0; ks < 2; ++ks){
        short8 af[4], bfr[4];
        #pragma unroll
        for (int wm = 0; wm < 4; ++wm) af[wm] = *(const short8*)&tA[aoff[ks][wm]];
        #pragma unroll
        for (int wn = 0; wn < 4; ++wn) bfr[wn] = *(const short8*)&tB[boff[ks][wn]];
        #pragma unroll
        for (int wm = 0; wm < 4; ++wm)
          #pragma unroll
          for (int wn = 0; wn < 4; ++wn)
            acc[wm][wn] = __builtin_amdgcn_mfma_f32_16x16x32_bf16(af[wm], bfr[wn], acc[wm][wn], 0, 0, 0);
      }
      __syncthreads();
    }
  }

  // ---- epilogue: LSTM cell, store-only tail ----
  const int pb = nt * 128 + wave_n * 64 + l16;
  const float bi = biasp[pb], bf_ = biasp[pb + 16], bg = biasp[pb + 32], bo = biasp[pb + 48];
  float wi = 0.f, wf = 0.f, wg = 0.f, wo = 0.f;
  if (IS_L0){ wi = W0p[pb]; wf = W0p[pb + 16]; wg = W0p[pb + 32]; wo = W0p[pb + 48]; }

  #pragma unroll
  for (int wm = 0; wm < 4; ++wm){
    #pragma unroll
    for (int reg = 0; reg < 4; ++reg){
      int b = m0 + wave_m * 64 + wm * 16 + qd * 4 + reg;
      float zi = acc[wm][0][reg] + bi;
      float zf = acc[wm][1][reg] + bf_;
      float zg = acc[wm][2][reg] + bg;
      float zo = acc[wm][3][reg] + bo;
      if (IS_L0){
        float xvv = xv[wm][reg];
        zi += xvv * wi; zf += xvv * wf; zg += xvv * wg; zo += xvv * wo;
      }
      int mkk = mk[wm][reg];
      size_t su = (size_t)b * U_ + u;
      float c_old = h2f(c_raw[wm][reg]);
      float i_ = sigm(zi), f_ = sigm(zf), g_ = tanh_fast(zg), o_ = sigm(zo);
      float c_new = f_ * c_old + i_ * g_;
      float h_new = o_ * tanh_fast(c_new);
      // masked: store back ORIGINAL bits (no double rounding)
      cbuf[su] = mkk ? f2h(c_new) : c_raw[wm][reg];
      hout[su] = mkk ? f2bf(h_new) : hp[wm][reg];
    }
  }
}

// ---------------------------------------------------------------------------
// One wavefront phase: L0(t=s), L1(t=s-1), L2(t=s-2) independent ->
// 768 blocks (3 tasks x 256 tiles) = 3 blocks/CU (12 waves/CU). task=lin>>8
// so blocks {lin, lin+256, lin+512} share a CU under round-robin dispatch:
// uniform per-CU load and shared mask/x cachelines. XCD = lin%8 = nt%8 ->
// per-XCD B slice ~1.25 MB, L2-resident across all 102 phases (r4-verified).
// ---------------------------------------------------------------------------
__global__ __launch_bounds__(256, 3) void lstm_phase(
    const ushort_t* __restrict__ Bt0, const ushort_t* __restrict__ Bt1,
    const ushort_t* __restrict__ Bt2, const float* __restrict__ biasp,
    const float* __restrict__ W0p, const float* __restrict__ x,
    const int* __restrict__ mask,
    ushort_t* h00, ushort_t* h01, ushort_t* h10, ushort_t* h11,
    ushort_t* h20, ushort_t* h21,
    ushort_t* c0, ushort_t* c1, ushort_t* c2,
    int s)
{
  __shared__ __align__(16) ushort_t tA[128 * 64];
  __shared__ __align__(16) ushort_t tB[128 * 64];

  const int lin  = blockIdx.x;
  const int task = lin >> 8;        // 0..2
  const int tile = lin & 255;       // 0..255
  const int mt = tile >> 4, nt = tile & 15;

  ushort_t* h0[2] = {h00, h01};
  ushort_t* h1[2] = {h10, h11};
  ushort_t* h2[2] = {h20, h21};

  if (task == 0){
    if (s >= 100) return;
    int t = s, p = t & 1;
    do_task<0>(h0[p], nullptr, Bt0, biasp, W0p, x, mask,
               c0, h0[p], h0[p ^ 1], t, mt, nt, tA, tB);
  } else if (task == 1){
    if (s < 1 || s > 100) return;
    int t = s - 1, p = t & 1;
    do_task<1>(h0[p ^ 1], h1[p], Bt1, biasp + NG_, nullptr, x, mask,
               c1, h1[p], h1[p ^ 1], t, mt, nt, tA, tB);
  } else {
    if (s < 2) return;
    int t = s - 2, p = t & 1;
    do_task<2>(h1[p ^ 1], h2[p], Bt2, biasp + 2 * NG_, nullptr, x, mask,
               c2, h2[p], h2[p ^ 1], t, mt, nt, tA, tB);
  }
}

// ---------------------------------------------------------------------------
// Head: logits = h2 @ Wd + bd, softmax. One wave per batch row.
// ---------------------------------------------------------------------------
__global__ __launch_bounds__(256) void head_softmax(
    const ushort_t* __restrict__ h2, const float* __restrict__ Wd,
    const float* __restrict__ bd, float* __restrict__ out)
{
  int wv = threadIdx.x >> 6, lane = threadIdx.x & 63;
  int row = blockIdx.x * 4 + wv;
  const ushort_t* hr = h2 + (size_t)row * U_;

  float acc[C_];
  #pragma unroll
  for (int c = 0; c < C_; ++c) acc[c] = 0.f;

  short8 hv = *(const short8*)&hr[lane * 8];
  #pragma unroll
  for (int j = 0; j < 8; ++j){
    float hf = bf2f((ushort_t)hv[j]);
    int k = lane * 8 + j;
    #pragma unroll
    for (int c = 0; c < C_; ++c) acc[c] += hf * Wd[k * C_ + c];
  }
  #pragma unroll
  for (int c = 0; c < C_; ++c){
    float v = acc[c];
    #pragma unroll
    for (int off = 32; off > 0; off >>= 1) v += __shfl_xor(v, off);
    acc[c] = v + bd[c];
  }
  float mx = acc[0];
  #pragma unroll
  for (int c = 1; c < C_; ++c) mx = fmaxf(mx, acc[c]);
  float e[C_]; float s = 0.f;
  #pragma unroll
  for (int c = 0; c < C_; ++c){ e[c] = __expf(acc[c] - mx); s += e[c]; }
  float inv = 1.0f / s;
  if (lane == 0){
    #pragma unroll
    for (int c = 0; c < C_; ++c) out[(size_t)row * C_ + c] = e[c] * inv;
  }
}

// ---------------------------------------------------------------------------
extern "C" void kernel_launch(void* const* d_in, const int* in_sizes, int n_in,
                              void* d_out, int out_size, void* d_ws, size_t ws_size,
                              hipStream_t stream)
{
  const float* x  = (const float*)d_in[0];
  const int*  mask= (const int*)  d_in[1];
  const float* W0 = (const float*)d_in[2];
  const float* U0 = (const float*)d_in[3];
  const float* b0 = (const float*)d_in[4];
  const float* W1 = (const float*)d_in[5];
  const float* U1 = (const float*)d_in[6];
  const float* b1 = (const float*)d_in[7];
  const float* W2 = (const float*)d_in[8];
  const float* U2 = (const float*)d_in[9];
  const float* b2 = (const float*)d_in[10];
  const float* Wd = (const float*)d_in[11];
  const float* bd = (const float*)d_in[12];
  float* out = (float*)d_out;

  char* ws = (char*)d_ws;
  size_t off = 0;
  auto alloc = [&](size_t sz) -> char* {
    char* p = ws + off; off = (off + sz + 255) & ~(size_t)255; return p;
  };
  ushort_t* Bt0  = (ushort_t*)alloc((size_t)NG_ * 512 * 2);
  ushort_t* Bt1  = (ushort_t*)alloc((size_t)NG_ * 1024 * 2);
  ushort_t* Bt2  = (ushort_t*)alloc((size_t)NG_ * 1024 * 2);
  float*    W0p  = (float*)alloc((size_t)NG_ * 4);
  float*    biasp= (float*)alloc((size_t)3 * NG_ * 4);

  // State: h[3][2] (bf16) + c[3] (fp16), one contiguous memset region.
  const size_t hsz = (size_t)B_ * U_ * 2;
  const size_t csz = (size_t)B_ * U_ * 2;
  char* state = alloc(6 * hsz + 3 * csz);
  ushort_t* hb[3][2]; ushort_t* cb[3];
  {
    char* pp = state;
    for (int l = 0; l < 3; ++l)
      for (int par = 0; par < 2; ++par){ hb[l][par] = (ushort_t*)pp; pp += hsz; }
    for (int l = 0; l < 3; ++l){ cb[l] = (ushort_t*)pp; pp += csz; }
  }

  hipMemsetAsync(state, 0, 6 * hsz + 3 * csz, stream);

  const int total = NG_ * 512 + 2 * NG_ * 1024 + NG_ + 3 * NG_;
  convert_weights<<<(total + 255) / 256, 256, 0, stream>>>(
      W0, U0, b0, W1, U1, b1, W2, U2, b2, Bt0, Bt1, Bt2, W0p, biasp);

  for (int s = 0; s < 102; ++s){
    lstm_phase<<<768, 256, 0, stream>>>(
        Bt0, Bt1, Bt2, biasp, W0p, x, mask,
        hb[0][0], hb[0][1], hb[1][0], hb[1][1], hb[2][0], hb[2][1],
        cb[0], cb[1], cb[2], s);
  }

  // T=100: layer-2 final h (t=99) lands in parity-0 buffer.
  head_softmax<<<B_ / 4, 256, 0, stream>>>(hb[2][0], Wd, bd, out);
}

// Round 9
// 3928.062 us; speedup vs baseline: 1.6494x; 1.3287x over previous
//
#include <hip/hip_runtime.h>
#include <cstdint>
#include <cstddef>

// Problem constants (fixed by the reference).
#define B_   2048
#define T_   100
#define U_   512
#define NG_  2048   // 4*U
#define C_   10

typedef __attribute__((ext_vector_type(8))) short          short8;
typedef __attribute__((ext_vector_type(8))) unsigned short ushort8;
typedef __attribute__((ext_vector_type(4))) float          floatx4;
typedef unsigned short ushort_t;

__device__ inline ushort_t f2bf(float f){
  unsigned u = __float_as_uint(f);
  unsigned r = (u + 0x7FFFu + ((u >> 16) & 1u)) >> 16;   // RNE
  return (ushort_t)r;
}
__device__ inline float bf2f(ushort_t b){ return __uint_as_float(((unsigned)b) << 16); }

// fp16 storage for c-state (layer-private): |c| <= ~100, fp16 rel-err 2^-11 —
// negligible vs bf16 GEMM noise; halves c traffic.
__device__ inline ushort_t f2h(float f){
  _Float16 h = (_Float16)f;
  return __builtin_bit_cast(ushort_t, h);
}
__device__ inline float h2f(ushort_t u){
  _Float16 h = __builtin_bit_cast(_Float16, u);
  return (float)h;
}

__device__ inline float sigm(float x){ return 1.0f / (1.0f + __expf(-x)); }
__device__ inline float tanh_fast(float x){
  float a = fabsf(x);
  float e = __expf(-2.0f * a);          // no overflow: e in (0,1]
  float r = (1.0f - e) / (1.0f + e);
  return copysignf(r, x);
}

// Column permutation: permuted col p -> original gate-major col.
// Tile T (128 cols) owns u in [T*32, T*32+32); within tile: two 64-col halves,
// each half = 4 gates x 16 u's, gate-major in 16-col groups.
__device__ inline int orig_col(int p){
  int Tt  = p >> 7;
  int loc = p & 127;
  int half = loc >> 6;
  int loc2 = loc & 63;
  int gate = loc2 >> 4;
  int uu   = (half << 4) | (loc2 & 15);
  return gate * U_ + Tt * 32 + uu;
}

#define AS1(p) ((const __attribute__((address_space(1))) void*)(p))
#define AS3(p) ((__attribute__((address_space(3))) void*)(p))

// ---------------------------------------------------------------------------
// One-time (per launch) repack: weights fp32 -> bf16 B^T permuted layout,
// permuted biases + W0 row, and TRANSPOSED mask/x copies (maskT[t][b],
// xT[t][b]) so the LSTM epilogue reads them as coalesced int4/float4 instead
// of 400-B-strided scattered dwords.
// ---------------------------------------------------------------------------
__global__ void convert_weights(
    const float* __restrict__ W0, const float* __restrict__ U0, const float* __restrict__ b0,
    const float* __restrict__ W1, const float* __restrict__ U1, const float* __restrict__ b1,
    const float* __restrict__ W2, const float* __restrict__ U2, const float* __restrict__ b2,
    const float* __restrict__ x, const int* __restrict__ mask,
    ushort_t* __restrict__ Bt0, ushort_t* __restrict__ Bt1, ushort_t* __restrict__ Bt2,
    float* __restrict__ W0p, float* __restrict__ biasp,
    int* __restrict__ maskT, float* __restrict__ xT)
{
  const int N0 = NG_ * 512;     // Bt0 elements
  const int N1 = NG_ * 1024;    // Bt1/Bt2 elements
  const int TB = T_ * B_;
  const int S5 = N0 + 2 * N1 + NG_ + 3 * NG_;
  const int total = S5 + 2 * TB;
  int idx = blockIdx.x * 256 + threadIdx.x;
  if (idx >= total) return;

  if (idx < N0){
    int p = idx >> 9, k = idx & 511;
    Bt0[idx] = f2bf(U0[(size_t)k * NG_ + orig_col(p)]);
  } else if (idx < N0 + N1){
    int j = idx - N0; int p = j >> 10, k = j & 1023;
    int oc = orig_col(p);
    float v = (k < 512) ? W1[(size_t)k * NG_ + oc] : U1[(size_t)(k - 512) * NG_ + oc];
    Bt1[j] = f2bf(v);
  } else if (idx < N0 + 2 * N1){
    int j = idx - N0 - N1; int p = j >> 10, k = j & 1023;
    int oc = orig_col(p);
    float v = (k < 512) ? W2[(size_t)k * NG_ + oc] : U2[(size_t)(k - 512) * NG_ + oc];
    Bt2[j] = f2bf(v);
  } else if (idx < N0 + 2 * N1 + NG_){
    int p = idx - N0 - 2 * N1;
    W0p[p] = W0[orig_col(p)];
  } else if (idx < S5){
    int j = idx - N0 - 2 * N1 - NG_;
    int l = j >> 11, p = j & 2047;
    const float* bs = (l == 0) ? b0 : (l == 1) ? b1 : b2;
    biasp[j] = bs[orig_col(p)];
  } else if (idx < S5 + TB){
    int j = idx - S5;
    int tt = j >> 11, b = j & 2047;       // B_ = 2048
    maskT[j] = mask[(size_t)b * T_ + tt];
  } else {
    int j = idx - S5 - TB;
    int tt = j >> 11, b = j & 2047;
    xT[j] = x[(size_t)b * T_ + tt];
  }
}

// ---------------------------------------------------------------------------
// Fused GEMM (bf16 MFMA) + LSTM cell for one (layer, timestep),
// 128x128 tile at (mt, nt). BK=64 2-barrier K-loop (round-4 winner; dbuf,
// BK=32, wide/small tiles, and cross-loop prefetch arrays all regressed —
// the last one via scratch spills, r8). Slot rotation: LDS slot (r,j) holds
// global 16B-chunk (j+r)&7, readback (q-r)&7 -> bank conflicts measured 0.
// c-state in fp16, FRAGMENT-CONTIGUOUS layout (layer-private, never feeds a
// GEMM): each thread's 16 c-values are one 32B chunk -> coalesced r/w.
// 256 threads = 2x2 waves, each wave 4x4 frags of 16x16x32, 2 k-steps/iter.
// ---------------------------------------------------------------------------
template<int LAYER>
__device__ __forceinline__ void do_task(
    const ushort_t* __restrict__ A0,   // phase-0 A (h_below / h_prev for L0)
    const ushort_t* __restrict__ A1,   // phase-1 A (h_prev), LAYER>0
    const ushort_t* __restrict__ Bt,   // (2048 x K) bf16, n-major permuted
    const float* __restrict__ biasp,   // permuted bias for this layer (2048)
    const float* __restrict__ W0p,     // permuted W0 row (L0 only)
    const float* __restrict__ xT,      // (T,B) fp32 transposed (L0 only)
    const int* __restrict__ maskT,     // (T,B) int32 transposed
    ushort_t* __restrict__ cbuf,       // (B*U) fp16, fragment layout, in/out
    const ushort_t* __restrict__ hprev,// this layer's previous h (mask carry)
    ushort_t* __restrict__ hout,       // (B,U) bf16 out
    int t, int mt, int nt,
    ushort_t* tA, ushort_t* tB)
{
  constexpr int NPHASE = (LAYER == 0) ? 1 : 2;
  constexpr bool IS_L0 = (LAYER == 0);
  constexpr int K = NPHASE * 512;

  const int tid  = threadIdx.x;
  const int wv   = tid >> 6;
  const int lane = tid & 63;
  const int qd   = lane >> 4;     // quad 0..3
  const int l16  = lane & 15;
  const int wave_m = wv >> 1;     // 0..1
  const int wave_n = wv & 1;      // 0..1
  const int m0 = mt * 128, n0 = nt * 128;

  // Staging identity: 1024 16B-chunks per 128x64 tile, 4/thread.
  // Source 16B-col sc = ((i&7) + r) & 7  (row rotation).
  int srow[4], scol[4];
  #pragma unroll
  for (int g = 0; g < 4; ++g){
    int i = g * 256 + tid;
    srow[g] = i >> 3;
    scol[g] = ((i & 7) + (i >> 3)) & 7;
  }

  // Readback: frag row R wants global chunk q = ks*4+qd at slot (q-R)&7.
  int aoff[2][4], boff[2][4];
  #pragma unroll
  for (int ks = 0; ks < 2; ++ks){
    int q = ks * 4 + qd;
    #pragma unroll
    for (int w = 0; w < 4; ++w){
      int Ra = wave_m * 64 + w * 16 + l16;
      int Rb = wave_n * 64 + w * 16 + l16;
      aoff[ks][w] = Ra * 64 + ((q - Ra) & 7) * 8;
      boff[ks][w] = Rb * 64 + ((q - Rb) & 7) * 8;
    }
  }

  floatx4 acc[4][4];
  #pragma unroll
  for (int i = 0; i < 4; ++i)
    #pragma unroll
    for (int j = 0; j < 4; ++j) acc[i][j] = (floatx4){0.f, 0.f, 0.f, 0.f};

  #pragma unroll
  for (int ph = 0; ph < NPHASE; ++ph){
    const ushort_t* A = (NPHASE == 2 && ph == 1) ? A1 : A0;
    for (int k0 = 0; k0 < 512; k0 += 64){
      #pragma unroll
      for (int g = 0; g < 4; ++g){
        int ibase = g * 256 + wv * 64;
        const ushort_t* ga = A + (size_t)(m0 + srow[g]) * U_ + k0 + scol[g] * 8;
        __builtin_amdgcn_global_load_lds(AS1(ga), AS3(&tA[ibase * 8]), 16, 0, 0);
        const ushort_t* gb = Bt + (size_t)(n0 + srow[g]) * K + ph * 512 + k0 + scol[g] * 8;
        __builtin_amdgcn_global_load_lds(AS1(gb), AS3(&tB[ibase * 8]), 16, 0, 0);
      }
      __syncthreads();

      #pragma unroll
      for (int ks = 0; ks < 2; ++ks){
        short8 af[4], bfr[4];
        #pragma unroll
        for (int wm = 0; wm < 4; ++wm) af[wm] = *(const short8*)&tA[aoff[ks][wm]];
        #pragma unroll
        for (int wn = 0; wn < 4; ++wn) bfr[wn] = *(const short8*)&tB[boff[ks][wn]];
        #pragma unroll
        for (int wm = 0; wm < 4; ++wm)
          #pragma unroll
          for (int wn = 0; wn < 4; ++wn)
            acc[wm][wn] = __builtin_amdgcn_mfma_f32_16x16x32_bf16(af[wm], bfr[wn], acc[wm][wn], 0, 0, 0);
      }
      __syncthreads();
    }
  }

  // ---- epilogue: LSTM cell, coalesced c / vectorized mask & x ----
  const int u  = nt * 32 + wave_n * 16 + l16;
  const int pb = nt * 128 + wave_n * 64 + l16;
  const float bi = biasp[pb], bf_ = biasp[pb + 16], bg = biasp[pb + 32], bo = biasp[pb + 48];
  float wi = 0.f, wf = 0.f, wg = 0.f, wo = 0.f;
  if (IS_L0){ wi = W0p[pb]; wf = W0p[pb + 16]; wg = W0p[pb + 32]; wo = W0p[pb + 48]; }

  ushort_t* cfrag = cbuf + (((size_t)((mt * 16 + nt) * 256 + tid)) << 4);
  ushort8 co0 = *(const ushort8*)cfrag;
  ushort8 co1 = *(const ushort8*)(cfrag + 8);
  ushort8 cn0, cn1;

  #pragma unroll
  for (int wm = 0; wm < 4; ++wm){
    int b0 = m0 + wave_m * 64 + wm * 16 + qd * 4;
    const int4   mkv = *(const int4*)&maskT[(size_t)t * B_ + b0];
    float4 xq;
    if (IS_L0) xq = *(const float4*)&xT[(size_t)t * B_ + b0];
    const int*   mkp = (const int*)&mkv;
    const float* xp  = (const float*)&xq;

    #pragma unroll
    for (int reg = 0; reg < 4; ++reg){
      int item = wm * 4 + reg;
      ushort_t craw = (item < 8) ? co0[item] : co1[item - 8];
      int mkk = mkp[reg];
      float zi = acc[wm][0][reg] + bi;
      float zf = acc[wm][1][reg] + bf_;
      float zg = acc[wm][2][reg] + bg;
      float zo = acc[wm][3][reg] + bo;
      if (IS_L0){
        float xvv = xp[reg];
        zi += xvv * wi; zf += xvv * wf; zg += xvv * wg; zo += xvv * wo;
      }
      float c_old = h2f(craw);
      float i_ = sigm(zi), f_ = sigm(zf), g_ = tanh_fast(zg), o_ = sigm(zo);
      float c_new = f_ * c_old + i_ * g_;
      float h_new = o_ * tanh_fast(c_new);
      ushort_t cnew = mkk ? f2h(c_new) : craw;   // masked: original bits
      if (item < 8) cn0[item] = cnew; else cn1[item - 8] = cnew;
      size_t su = (size_t)(b0 + reg) * U_ + u;
      hout[su] = mkk ? f2bf(h_new) : hprev[su];
    }
  }
  *(ushort8*)cfrag       = cn0;
  *(ushort8*)(cfrag + 8) = cn1;
}

// ---------------------------------------------------------------------------
// One wavefront phase: L0(t=s), L1(t=s-1), L2(t=s-2) independent ->
// 768 blocks (3 tasks x 256 tiles) = 3 blocks/CU (12 waves/CU). task=lin>>8
// so blocks {lin, lin+256, lin+512} share a CU under round-robin dispatch:
// uniform per-CU load and shared mask/x cachelines. XCD = lin%8 = nt%8 ->
// per-XCD B slice ~1.25 MB, L2-resident across all 102 phases (r4-verified).
// Plain launch_bounds(256): grid gives 3 blocks/CU; no VGPR cap -> no spill
// (r8 lesson: the (256,3) cap + extra live state caused scratch traffic).
// ---------------------------------------------------------------------------
__global__ __launch_bounds__(256) void lstm_phase(
    const ushort_t* __restrict__ Bt0, const ushort_t* __restrict__ Bt1,
    const ushort_t* __restrict__ Bt2, const float* __restrict__ biasp,
    const float* __restrict__ W0p, const float* __restrict__ xT,
    const int* __restrict__ maskT,
    ushort_t* h00, ushort_t* h01, ushort_t* h10, ushort_t* h11,
    ushort_t* h20, ushort_t* h21,
    ushort_t* c0, ushort_t* c1, ushort_t* c2,
    int s)
{
  __shared__ __align__(16) ushort_t tA[128 * 64];
  __shared__ __align__(16) ushort_t tB[128 * 64];

  const int lin  = blockIdx.x;
  const int task = lin >> 8;        // 0..2
  const int tile = lin & 255;       // 0..255
  const int mt = tile >> 4, nt = tile & 15;

  ushort_t* h0[2] = {h00, h01};
  ushort_t* h1[2] = {h10, h11};
  ushort_t* h2[2] = {h20, h21};

  if (task == 0){
    if (s >= 100) return;
    int t = s, p = t & 1;
    do_task<0>(h0[p], nullptr, Bt0, biasp, W0p, xT, maskT,
               c0, h0[p], h0[p ^ 1], t, mt, nt, tA, tB);
  } else if (task == 1){
    if (s < 1 || s > 100) return;
    int t = s - 1, p = t & 1;
    do_task<1>(h0[p ^ 1], h1[p], Bt1, biasp + NG_, nullptr, nullptr, maskT,
               c1, h1[p], h1[p ^ 1], t, mt, nt, tA, tB);
  } else {
    if (s < 2) return;
    int t = s - 2, p = t & 1;
    do_task<2>(h1[p ^ 1], h2[p], Bt2, biasp + 2 * NG_, nullptr, nullptr, maskT,
               c2, h2[p], h2[p ^ 1], t, mt, nt, tA, tB);
  }
}

// ---------------------------------------------------------------------------
// Head: logits = h2 @ Wd + bd, softmax. One wave per batch row.
// ---------------------------------------------------------------------------
__global__ __launch_bounds__(256) void head_softmax(
    const ushort_t* __restrict__ h2, const float* __restrict__ Wd,
    const float* __restrict__ bd, float* __restrict__ out)
{
  int wv = threadIdx.x >> 6, lane = threadIdx.x & 63;
  int row = blockIdx.x * 4 + wv;
  const ushort_t* hr = h2 + (size_t)row * U_;

  float acc[C_];
  #pragma unroll
  for (int c = 0; c < C_; ++c) acc[c] = 0.f;

  short8 hv = *(const short8*)&hr[lane * 8];
  #pragma unroll
  for (int j = 0; j < 8; ++j){
    float hf = bf2f((ushort_t)hv[j]);
    int k = lane * 8 + j;
    #pragma unroll
    for (int c = 0; c < C_; ++c) acc[c] += hf * Wd[k * C_ + c];
  }
  #pragma unroll
  for (int c = 0; c < C_; ++c){
    float v = acc[c];
    #pragma unroll
    for (int off = 32; off > 0; off >>= 1) v += __shfl_xor(v, off);
    acc[c] = v + bd[c];
  }
  float mx = acc[0];
  #pragma unroll
  for (int c = 1; c < C_; ++c) mx = fmaxf(mx, acc[c]);
  float e[C_]; float s = 0.f;
  #pragma unroll
  for (int c = 0; c < C_; ++c){ e[c] = __expf(acc[c] - mx); s += e[c]; }
  float inv = 1.0f / s;
  if (lane == 0){
    #pragma unroll
    for (int c = 0; c < C_; ++c) out[(size_t)row * C_ + c] = e[c] * inv;
  }
}

// ---------------------------------------------------------------------------
extern "C" void kernel_launch(void* const* d_in, const int* in_sizes, int n_in,
                              void* d_out, int out_size, void* d_ws, size_t ws_size,
                              hipStream_t stream)
{
  const float* x  = (const float*)d_in[0];
  const int*  mask= (const int*)  d_in[1];
  const float* W0 = (const float*)d_in[2];
  const float* U0 = (const float*)d_in[3];
  const float* b0 = (const float*)d_in[4];
  const float* W1 = (const float*)d_in[5];
  const float* U1 = (const float*)d_in[6];
  const float* b1 = (const float*)d_in[7];
  const float* W2 = (const float*)d_in[8];
  const float* U2 = (const float*)d_in[9];
  const float* b2 = (const float*)d_in[10];
  const float* Wd = (const float*)d_in[11];
  const float* bd = (const float*)d_in[12];
  float* out = (float*)d_out;

  char* ws = (char*)d_ws;
  size_t off = 0;
  auto alloc = [&](size_t sz) -> char* {
    char* p = ws + off; off = (off + sz + 255) & ~(size_t)255; return p;
  };
  ushort_t* Bt0  = (ushort_t*)alloc((size_t)NG_ * 512 * 2);
  ushort_t* Bt1  = (ushort_t*)alloc((size_t)NG_ * 1024 * 2);
  ushort_t* Bt2  = (ushort_t*)alloc((size_t)NG_ * 1024 * 2);
  float*    W0p  = (float*)alloc((size_t)NG_ * 4);
  float*    biasp= (float*)alloc((size_t)3 * NG_ * 4);
  int*      maskT= (int*)alloc((size_t)T_ * B_ * 4);
  float*    xT   = (float*)alloc((size_t)T_ * B_ * 4);

  // State: h[3][2] (bf16) + c[3] (fp16, fragment layout), one memset region.
  const size_t hsz = (size_t)B_ * U_ * 2;
  const size_t csz = (size_t)B_ * U_ * 2;
  char* state = alloc(6 * hsz + 3 * csz);
  ushort_t* hb[3][2]; ushort_t* cb[3];
  {
    char* pp = state;
    for (int l = 0; l < 3; ++l)
      for (int par = 0; par < 2; ++par){ hb[l][par] = (ushort_t*)pp; pp += hsz; }
    for (int l = 0; l < 3; ++l){ cb[l] = (ushort_t*)pp; pp += csz; }
  }

  hipMemsetAsync(state, 0, 6 * hsz + 3 * csz, stream);

  const int TB = T_ * B_;
  const int total = NG_ * 512 + 2 * NG_ * 1024 + NG_ + 3 * NG_ + 2 * TB;
  convert_weights<<<(total + 255) / 256, 256, 0, stream>>>(
      W0, U0, b0, W1, U1, b1, W2, U2, b2, x, mask,
      Bt0, Bt1, Bt2, W0p, biasp, maskT, xT);

  for (int s = 0; s < 102; ++s){
    lstm_phase<<<768, 256, 0, stream>>>(
        Bt0, Bt1, Bt2, biasp, W0p, xT, maskT,
        hb[0][0], hb[0][1], hb[1][0], hb[1][1], hb[2][0], hb[2][1],
        cb[0], cb[1], cb[2], s);
  }

  // T=100: layer-2 final h (t=99) lands in parity-0 buffer.
  head_softmax<<<B_ / 4, 256, 0, stream>>>(hb[2][0], Wd, bd, out);
}